// Round 1
// baseline (659.535 us; speedup 1.0000x reference)
//
#include <hip/hip_runtime.h>

#define D_MODEL 1024
#define LSEQ    8192
#define NC      8192            // complex FFT size = (2*L)/2
#define PI_F    3.14159265358979323846f
#define TWO_PI_OVER_N 3.8349519697141029e-4f   // 2*pi/16384

// XOR swizzle on LDS float2 index: kills the stride-128 (64-way) bank
// conflicts of the bit-reversed middle pass; unit-stride runs stay
// conflict-free (runs of 64 are 64-aligned -> (p>>7) constant per wave).
__device__ __forceinline__ int sw(int p) { return p ^ ((p >> 7) & 15); }
__device__ __forceinline__ int rev13(int x) { return (int)(__brev((unsigned)x) >> 19); }
__device__ __forceinline__ float2 cmulf(float2 a, float2 b) {
    return make_float2(a.x*b.x - a.y*b.y, a.x*b.y + a.y*b.x);
}

// In-place DIF (Gentleman-Sande), natural input -> bit-reversed output.
__device__ __forceinline__ void fft_fwd(float2* s, int tid) {
    for (int h = 4096; h >= 1; h >>= 1) {
        __syncthreads();
        float astep = -PI_F / (float)h;      // w = e^{-i*pi*pos/h}
        #pragma unroll
        for (int j = 0; j < 16; ++j) {
            int idx = tid + j * 256;         // 0..4095
            int pos = idx & (h - 1);
            int i0  = 2 * idx - pos;         // grp*2h + pos
            int a0 = sw(i0), a1 = sw(i0 + h);
            float2 a = s[a0], b = s[a1];
            float sn, cs;
            __sincosf(astep * (float)pos, &sn, &cs);
            s[a0] = make_float2(a.x + b.x, a.y + b.y);
            float vx = a.x - b.x, vy = a.y - b.y;
            s[a1] = make_float2(vx * cs - vy * sn, vx * sn + vy * cs);
        }
    }
}

// In-place DIT (Cooley-Tukey), bit-reversed input -> natural output,
// UNNORMALIZED inverse (conjugate twiddles).
__device__ __forceinline__ void fft_inv(float2* s, int tid) {
    for (int h = 1; h <= 4096; h <<= 1) {
        __syncthreads();
        float astep = PI_F / (float)h;       // w = e^{+i*pi*pos/h}
        #pragma unroll
        for (int j = 0; j < 16; ++j) {
            int idx = tid + j * 256;
            int pos = idx & (h - 1);
            int i0  = 2 * idx - pos;
            int a0 = sw(i0), a1 = sw(i0 + h);
            float2 a = s[a0], b = s[a1];
            float sn, cs;
            __sincosf(astep * (float)pos, &sn, &cs);
            float bx = b.x * cs - b.y * sn, by = b.x * sn + b.y * cs;
            s[a0] = make_float2(a.x + bx, a.y + by);
            s[a1] = make_float2(a.x - bx, a.y - by);
        }
    }
}

// ---------------------------------------------------------------------------
// Kernel 1: implicit-filter MLP + output projection + exponential modulation.
// Writes time-domain k[d][l] (row-major [1024][8192]) into kout.
// grid (128, 4): blockIdx.x = 64-position tile, blockIdx.y = 256-channel tile.
// ---------------------------------------------------------------------------
__global__ void __launch_bounds__(256) hyena_filter_k(
    const float* __restrict__ W1, const float* __restrict__ b1,
    const float* __restrict__ freq,
    const float* __restrict__ W2, const float* __restrict__ b2,
    const float* __restrict__ W3, const float* __restrict__ b3,
    const float* __restrict__ Wout,
    float* __restrict__ kout)
{
    __shared__ float zbuf[64][35];   // pad 33->35: (3p+e)%32 -> 2-way (free)
    __shared__ float abuf[64][65];   // pad 64->65: (p+o)%32  -> 2-way (free)
    __shared__ float bbuf[64][65];

    const int tid = threadIdx.x;
    const int pbase = blockIdx.x * 64;

    // phase 0: positional embedding z[p][0..32]
    for (int idx = tid; idx < 64 * 33; idx += 256) {
        int p = idx & 63, e = idx >> 6;
        int gp = pbase + p;
        float w = 7.6699039394282907e-4f * (float)gp;   // 2*pi*gp/8192
        float val;
        if (e == 0) {
            val = (float)gp / 8191.0f;                  // t
        } else if (e < 17) {
            float f = 1.0e-4f + (float)(e - 1) * ((15.0f - 1.0e-4f) / 15.0f);
            val = cosf(f * w);
        } else {
            float f = 1.0e-4f + (float)(e - 17) * ((15.0f - 1.0e-4f) / 15.0f);
            val = -sinf(f * w);
        }
        zbuf[p][e] = val;
    }
    __syncthreads();

    const int p = tid & 63;          // position within tile (wave-varying)
    const int g = tid >> 6;          // neuron group 0..3 (wave-uniform)

    // layer 1: 33 -> 64, sin(freq * (z@W1 + b1))
    for (int oo = 0; oo < 16; ++oo) {
        int o = g * 16 + oo;
        float acc = b1[o];
        #pragma unroll
        for (int e = 0; e < 33; ++e) acc += zbuf[p][e] * W1[e * 64 + o];
        abuf[p][o] = __sinf(freq[o] * acc);
    }
    __syncthreads();
    // layer 2
    for (int oo = 0; oo < 16; ++oo) {
        int o = g * 16 + oo;
        float acc = b2[o];
        #pragma unroll
        for (int e = 0; e < 64; ++e) acc += abuf[p][e] * W2[e * 64 + o];
        bbuf[p][o] = __sinf(freq[o] * acc);
    }
    __syncthreads();
    // layer 3
    for (int oo = 0; oo < 16; ++oo) {
        int o = g * 16 + oo;
        float acc = b3[o];
        #pragma unroll
        for (int e = 0; e < 64; ++e) acc += bbuf[p][e] * W3[e * 64 + o];
        abuf[p][o] = __sinf(freq[o] * acc);
    }
    __syncthreads();

    // out projection (no bias, no sin) + decay, write k[d][l]
    const int gp = pbase + p;
    const float t = (float)gp / 8191.0f;
    const float mind  = -3.0701134573253940f;    // log(0.01)/1.5
    const float dstep = -0.012004353694331942f;  // (log(.01)/.3 - log(.01)/1.5)/1023
    for (int i = 0; i < 64; ++i) {
        int dd = blockIdx.y * 256 + g + 4 * i;   // wave-uniform channel
        float acc = 0.0f;
        #pragma unroll
        for (int o = 0; o < 64; ++o) acc += abuf[p][o] * Wout[o * 1024 + dd];
        float delta = fabsf(mind + dstep * (float)dd);
        kout[(size_t)dd * LSEQ + gp] = acc * __expf(-t * delta);
    }
}

// ---------------------------------------------------------------------------
// Kernel 2: per-channel FFT causal convolution + skip.
// One block per channel d; handles both batches.
//   real FFT of size 16384 via packed complex FFT of size 8192 in LDS (64 KB).
//   Filter spectrum kept in registers (Kk/Km, already scaled by 1/N).
// ---------------------------------------------------------------------------
__global__ void __launch_bounds__(256) hyena_conv_k(
    const float* __restrict__ x, const float* kin,
    const float* __restrict__ Dvec, float* out)
{
    __shared__ float2 s[NC];                     // 64 KB
    const int tid = threadIdx.x;
    const int d = blockIdx.x;
    const float Dd = Dvec[d];
    const float invN = 1.0f / 16384.0f;

    // ---- phase A: FFT of filter k[d], unpack spectrum into registers ----
    {
        const float2* kb = (const float2*)(kin + (size_t)d * LSEQ);
        #pragma unroll
        for (int i = 0; i < 16; ++i) { int n = tid + i * 256; s[sw(n)] = kb[n]; }
        #pragma unroll
        for (int i = 16; i < 32; ++i) { int n = tid + i * 256; s[sw(n)] = make_float2(0.f, 0.f); }
    }
    fft_fwd(s, tid);
    __syncthreads();

    float2 Kk[16], Km[16];   // K[k]/N and K[8192-k]/N for k = tid + j*256
    #pragma unroll
    for (int j = 0; j < 16; ++j) {
        int k = tid + j * 256;
        if (k == 0) {
            float2 C0 = s[0];                       // sw(0)==0
            Kk[0] = make_float2((C0.x + C0.y) * invN, (C0.x - C0.y) * invN); // (K[0],K[8192])/N
            float2 C = s[1];                        // C[4096] at rev13(4096)=1, sw(1)==1
            Km[0] = make_float2(C.x * invN, -C.y * invN);                    // conj(C)/N
        } else {
            int m = NC - k;
            float2 Ck = s[sw(rev13(k))], Cm = s[sw(rev13(m))];
            float sn, cs;
            __sincosf(TWO_PI_OVER_N * (float)k, &sn, &cs);   // w = (cs,-sn)
            float2 E = make_float2(Ck.x + Cm.x, Ck.y - Cm.y); // Ck + conj(Cm)
            float2 O = make_float2(Ck.x - Cm.x, Ck.y + Cm.y); // Ck - conj(Cm)
            float2 WO = make_float2(O.x * cs + O.y * sn, -O.x * sn + O.y * cs); // w*O
            float2 T = make_float2(-WO.y, WO.x);              // i*w*O
            Kk[j] = make_float2(0.5f * invN * (E.x - T.x),  0.5f * invN * (E.y - T.y));
            Km[j] = make_float2(0.5f * invN * (E.x + T.x), -0.5f * invN * (E.y + T.y)); // conj(E+T)/2N
        }
    }

    // ---- per-batch: FFT(x) -> multiply -> IFFT -> + x*D ----
    for (int b = 0; b < 2; ++b) {
        __syncthreads();   // prior readers of s are done
        const size_t base = ((size_t)b * D_MODEL + d) * LSEQ;
        const float2* xv = (const float2*)(x + base);
        float2 xr[16];
        #pragma unroll
        for (int i = 0; i < 16; ++i) {
            int n = tid + i * 256;
            float2 v = xv[n];
            s[sw(n)] = v;
            xr[i] = v;
        }
        #pragma unroll
        for (int i = 16; i < 32; ++i) { int n = tid + i * 256; s[sw(n)] = make_float2(0.f, 0.f); }

        fft_fwd(s, tid);
        __syncthreads();

        // unpack U, multiply by filter spectrum, repack Z2 (x2 folded in),
        // all in bit-reversed layout.
        #pragma unroll
        for (int j = 0; j < 16; ++j) {
            int k = tid + j * 256;
            if (k == 0) {
                float2 C0 = s[0];
                float U0 = C0.x + C0.y, UN = C0.x - C0.y;   // U[0], U[8192] (real)
                float Y0 = U0 * Kk[0].x, YN = UN * Kk[0].y;
                s[0] = make_float2(Y0 + YN, Y0 - YN);       // Z2[0]
                float2 C = s[1];                            // C[4096]
                float2 U = make_float2(C.x, -C.y);          // U[4096] = conj(C)
                float2 Y = cmulf(U, Km[0]);
                s[1] = make_float2(2.0f * Y.x, -2.0f * Y.y); // Z2[4096] = 2*conj(Y)
            } else {
                int m = NC - k;
                int pk = sw(rev13(k)), pm = sw(rev13(m));
                float2 Ck = s[pk], Cm = s[pm];
                float sn, cs;
                __sincosf(TWO_PI_OVER_N * (float)k, &sn, &cs);   // w = (cs,-sn)
                float2 E = make_float2(Ck.x + Cm.x, Ck.y - Cm.y);
                float2 O = make_float2(Ck.x - Cm.x, Ck.y + Cm.y);
                float2 WO = make_float2(O.x * cs + O.y * sn, -O.x * sn + O.y * cs);
                float2 T = make_float2(-WO.y, WO.x);
                float2 Uk = make_float2(0.5f * (E.x - T.x),  0.5f * (E.y - T.y));
                float2 Um = make_float2(0.5f * (E.x + T.x), -0.5f * (E.y + T.y));
                float2 Yk = cmulf(Uk, Kk[j]);
                float2 Ym = cmulf(Um, Km[j]);
                float2 P = make_float2(Yk.x + Ym.x, Yk.y - Ym.y);  // Yk + conj(Ym)
                float2 Q = make_float2(Yk.x - Ym.x, Yk.y + Ym.y);  // Yk - conj(Ym)
                float2 CQ = make_float2(Q.x * cs - Q.y * sn, Q.x * sn + Q.y * cs); // conj(w)*Q
                float2 T2 = make_float2(-CQ.y, CQ.x);              // i*conj(w)*Q
                s[pk] = make_float2(P.x + T2.x, P.y + T2.y);       // Z2[k]
                s[pm] = make_float2(P.x - T2.x, -(P.y - T2.y));    // Z2[m] = conj(P-T2)
            }
        }

        fft_inv(s, tid);
        __syncthreads();

        float2* ov = (float2*)(out + base);
        #pragma unroll
        for (int i = 0; i < 16; ++i) {
            int n = tid + i * 256;
            float2 ys = s[sw(n)];
            ov[n] = make_float2(ys.x + xr[i].x * Dd, ys.y + xr[i].y * Dd);
        }
    }
}

extern "C" void kernel_launch(void* const* d_in, const int* in_sizes, int n_in,
                              void* d_out, int out_size, void* d_ws, size_t ws_size,
                              hipStream_t stream) {
    (void)in_sizes; (void)n_in; (void)out_size; (void)d_ws; (void)ws_size;
    const float* x    = (const float*)d_in[0];
    // d_in[1] is L (int scalar) -- constants are hardcoded (L=8192)
    const float* W1   = (const float*)d_in[2];
    const float* b1   = (const float*)d_in[3];
    const float* freq = (const float*)d_in[4];
    const float* W2   = (const float*)d_in[5];
    const float* b2   = (const float*)d_in[6];
    const float* W3   = (const float*)d_in[7];
    const float* b3   = (const float*)d_in[8];
    const float* Wout = (const float*)d_in[9];
    const float* Dv   = (const float*)d_in[10];
    float* out = (float*)d_out;

    // Time-domain filter k[1024][8192] lives in the b=0 half of d_out:
    // conv block d is the sole reader of k[d] and the sole (later) writer
    // of out[0][d] -- no cross-block hazard, no workspace needed.
    float* kbuf = out;

    hipLaunchKernelGGL(hyena_filter_k, dim3(128, 4), dim3(256), 0, stream,
                       W1, b1, freq, W2, b2, W3, b3, Wout, kbuf);
    hipLaunchKernelGGL(hyena_conv_k, dim3(1024), dim3(256), 0, stream,
                       x, kbuf, Dv, out);
}